// Round 1
// baseline (3189.853 us; speedup 1.0000x reference)
//
#include <hip/hip_runtime.h>
#include <math.h>

#ifndef M_PIf
#define M_PIf 3.14159265358979323846f
#endif

__device__ __forceinline__ float silu_f(float x) {
    return x / (1.0f + __expf(-x));
}

// ---------------- edge kernel ----------------
// LDS layout (floats)
#define EW1_OFF 0        // 72*32 = 2304
#define EB1_OFF 2304     // 32
#define EW2_OFF 2336     // 32*32 = 1024
#define EB2_OFF 3360     // 32
#define CW1_OFF 3392     // 32*32 = 1024
#define CB1_OFF 4416     // 32
#define CW2_OFF 4448     // 32
#define EDGE_W_TOTAL 4480

__global__ __launch_bounds__(256) void egc_edge_kernel(
    const float* __restrict__ coord,
    const float* __restrict__ node_feat,
    const int*   __restrict__ edge_index,
    const float* __restrict__ ff_coeff,
    const float* __restrict__ ew1, const float* __restrict__ eb1,
    const float* __restrict__ ew2, const float* __restrict__ eb2,
    const float* __restrict__ cw1, const float* __restrict__ cb1,
    const float* __restrict__ cw2,
    float* __restrict__ agg_h,   // [N,32] atomically accumulated
    float* __restrict__ agg_c,   // [N,3]
    float* __restrict__ counts,  // [N]
    int E)
{
    __shared__ float sw[EDGE_W_TOTAL];
    for (int t = threadIdx.x; t < 2304; t += 256) sw[EW1_OFF + t] = ew1[t];
    for (int t = threadIdx.x; t < 32;   t += 256) sw[EB1_OFF + t] = eb1[t];
    for (int t = threadIdx.x; t < 1024; t += 256) sw[EW2_OFF + t] = ew2[t];
    for (int t = threadIdx.x; t < 32;   t += 256) sw[EB2_OFF + t] = eb2[t];
    for (int t = threadIdx.x; t < 1024; t += 256) sw[CW1_OFF + t] = cw1[t];
    for (int t = threadIdx.x; t < 32;   t += 256) sw[CB1_OFF + t] = cb1[t];
    for (int t = threadIdx.x; t < 32;   t += 256) sw[CW2_OFF + t] = cw2[t];
    __syncthreads();

    const int e = blockIdx.x * 256 + threadIdx.x;
    if (e >= E) return;

    const int i = edge_index[e];
    const int j = edge_index[E + e];

    // coord2radial
    const float cix = coord[3*(size_t)i+0], ciy = coord[3*(size_t)i+1], ciz = coord[3*(size_t)i+2];
    const float cjx = coord[3*(size_t)j+0], cjy = coord[3*(size_t)j+1], cjz = coord[3*(size_t)j+2];
    const float cdx = cix - cjx, cdy = ciy - cjy, cdz = ciz - cjz;
    const float radial = cdx*cdx + cdy*cdy + cdz*cdz;

    // Fourier features: [cos(2pi*r*c0..c3), sin(2pi*r*c0..c3)]
    float ff[8];
    #pragma unroll
    for (int k = 0; k < 4; ++k) {
        float xp = (2.0f * M_PIf) * radial * ff_coeff[k];
        float s, c;
        sincosf(xp, &s, &c);   // accurate range reduction (xp can be O(500) rad)
        ff[k]     = c;
        ff[4 + k] = s;
    }

    // ---- edge MLP layer 1: in[72] @ ew1[72,32] + eb1 ----
    float acc[32];
    #pragma unroll
    for (int o = 0; o < 32; ++o) acc[o] = sw[EB1_OFF + o];

    {
        const float4* nfi4 = reinterpret_cast<const float4*>(node_feat + (size_t)i * 32);
        for (int q = 0; q < 8; ++q) {           // runtime loop: small code footprint
            float4 v = nfi4[q];
            float xs[4] = {v.x, v.y, v.z, v.w};
            const float* wr = &sw[EW1_OFF + q * 4 * 32];
            #pragma unroll
            for (int kk = 0; kk < 4; ++kk) {
                #pragma unroll
                for (int o = 0; o < 32; ++o)
                    acc[o] = fmaf(xs[kk], wr[kk*32 + o], acc[o]);
            }
        }
        const float4* nfj4 = reinterpret_cast<const float4*>(node_feat + (size_t)j * 32);
        for (int q = 0; q < 8; ++q) {
            float4 v = nfj4[q];
            float xs[4] = {v.x, v.y, v.z, v.w};
            const float* wr = &sw[EW1_OFF + (32 + q * 4) * 32];
            #pragma unroll
            for (int kk = 0; kk < 4; ++kk) {
                #pragma unroll
                for (int o = 0; o < 32; ++o)
                    acc[o] = fmaf(xs[kk], wr[kk*32 + o], acc[o]);
            }
        }
        #pragma unroll
        for (int k = 0; k < 8; ++k) {
            const float* wr = &sw[EW1_OFF + (64 + k) * 32];
            #pragma unroll
            for (int o = 0; o < 32; ++o)
                acc[o] = fmaf(ff[k], wr[o], acc[o]);
        }
    }

    float m1[32];
    #pragma unroll
    for (int o = 0; o < 32; ++o) m1[o] = silu_f(acc[o]);

    // ---- edge MLP layer 2: m1[32] @ ew2[32,32] + eb2 ----
    float m[32];
    #pragma unroll
    for (int o = 0; o < 32; ++o) m[o] = sw[EB2_OFF + o];
    #pragma unroll
    for (int h = 0; h < 32; ++h) {
        #pragma unroll
        for (int o = 0; o < 32; ++o)
            m[o] = fmaf(m1[h], sw[EW2_OFF + h*32 + o], m[o]);
    }
    #pragma unroll
    for (int o = 0; o < 32; ++o) m[o] = silu_f(m[o]);

    // ---- scatter message sum (node model input) ----
    {
        float* dst = agg_h + (size_t)i * 32;
        #pragma unroll
        for (int o = 0; o < 32; ++o) atomicAdd(&dst[o], m[o]);
    }

    // ---- coord head: w = silu(m @ cw1 + cb1) @ cw2 ----
    float c1[32];
    #pragma unroll
    for (int o = 0; o < 32; ++o) c1[o] = sw[CB1_OFF + o];
    #pragma unroll
    for (int h = 0; h < 32; ++h) {
        #pragma unroll
        for (int o = 0; o < 32; ++o)
            c1[o] = fmaf(m[h], sw[CW1_OFF + h*32 + o], c1[o]);
    }
    float w = 0.0f;
    #pragma unroll
    for (int o = 0; o < 32; ++o) w += silu_f(c1[o]) * sw[CW2_OFF + o];

    atomicAdd(&agg_c[(size_t)i*3 + 0], cdx * w);
    atomicAdd(&agg_c[(size_t)i*3 + 1], cdy * w);
    atomicAdd(&agg_c[(size_t)i*3 + 2], cdz * w);
    atomicAdd(&counts[i], 1.0f);
}

// ---------------- node kernel ----------------
#define NW1_OFF 0       // 64*32 = 2048
#define NB1_OFF 2048    // 32
#define NW2_OFF 2080    // 32*32 = 1024
#define NB2_OFF 3104    // 32
#define NODE_W_TOTAL 3136

__global__ __launch_bounds__(256) void egc_node_kernel(
    const float* __restrict__ coord,
    const float* __restrict__ node_feat,
    const float* __restrict__ agg_h,
    const float* __restrict__ agg_c,
    const float* __restrict__ counts,
    const float* __restrict__ nw1, const float* __restrict__ nb1,
    const float* __restrict__ nw2, const float* __restrict__ nb2,
    float* __restrict__ out_node,   // [N,32]
    float* __restrict__ out_coord,  // [N,3]
    int N)
{
    __shared__ float sw[NODE_W_TOTAL];
    for (int t = threadIdx.x; t < 2048; t += 256) sw[NW1_OFF + t] = nw1[t];
    for (int t = threadIdx.x; t < 32;   t += 256) sw[NB1_OFF + t] = nb1[t];
    for (int t = threadIdx.x; t < 1024; t += 256) sw[NW2_OFF + t] = nw2[t];
    for (int t = threadIdx.x; t < 32;   t += 256) sw[NB2_OFF + t] = nb2[t];
    __syncthreads();

    const int n = blockIdx.x * 256 + threadIdx.x;
    if (n >= N) return;

    float nf[32];
    {
        const float4* nf4 = reinterpret_cast<const float4*>(node_feat + (size_t)n * 32);
        #pragma unroll
        for (int q = 0; q < 8; ++q) {
            float4 v = nf4[q];
            nf[4*q+0] = v.x; nf[4*q+1] = v.y; nf[4*q+2] = v.z; nf[4*q+3] = v.w;
        }
    }

    // h1 = silu([nf, agg_h] @ nw1 + nb1)
    float acc[32];
    #pragma unroll
    for (int o = 0; o < 32; ++o) acc[o] = sw[NB1_OFF + o];
    #pragma unroll
    for (int k = 0; k < 32; ++k) {
        #pragma unroll
        for (int o = 0; o < 32; ++o)
            acc[o] = fmaf(nf[k], sw[NW1_OFF + k*32 + o], acc[o]);
    }
    {
        const float4* ah4 = reinterpret_cast<const float4*>(agg_h + (size_t)n * 32);
        for (int q = 0; q < 8; ++q) {
            float4 v = ah4[q];
            float xs[4] = {v.x, v.y, v.z, v.w};
            const float* wr = &sw[NW1_OFF + (32 + q * 4) * 32];
            #pragma unroll
            for (int kk = 0; kk < 4; ++kk) {
                #pragma unroll
                for (int o = 0; o < 32; ++o)
                    acc[o] = fmaf(xs[kk], wr[kk*32 + o], acc[o]);
            }
        }
    }
    float h1[32];
    #pragma unroll
    for (int o = 0; o < 32; ++o) h1[o] = silu_f(acc[o]);

    // h2 = h1 @ nw2 + nb2 ; out = nf + h2
    float h2[32];
    #pragma unroll
    for (int o = 0; o < 32; ++o) h2[o] = sw[NB2_OFF + o];
    #pragma unroll
    for (int k = 0; k < 32; ++k) {
        #pragma unroll
        for (int o = 0; o < 32; ++o)
            h2[o] = fmaf(h1[k], sw[NW2_OFF + k*32 + o], h2[o]);
    }

    {
        float4* on4 = reinterpret_cast<float4*>(out_node + (size_t)n * 32);
        #pragma unroll
        for (int q = 0; q < 8; ++q) {
            float4 v;
            v.x = nf[4*q+0] + h2[4*q+0];
            v.y = nf[4*q+1] + h2[4*q+1];
            v.z = nf[4*q+2] + h2[4*q+2];
            v.w = nf[4*q+3] + h2[4*q+3];
            on4[q] = v;
        }
    }

    const float cnt = fmaxf(counts[n], 1.0f);
    const float inv = 1.0f / cnt;
    out_coord[(size_t)n*3 + 0] = coord[(size_t)n*3 + 0] + agg_c[(size_t)n*3 + 0] * inv;
    out_coord[(size_t)n*3 + 1] = coord[(size_t)n*3 + 1] + agg_c[(size_t)n*3 + 1] * inv;
    out_coord[(size_t)n*3 + 2] = coord[(size_t)n*3 + 2] + agg_c[(size_t)n*3 + 2] * inv;
}

extern "C" void kernel_launch(void* const* d_in, const int* in_sizes, int n_in,
                              void* d_out, int out_size, void* d_ws, size_t ws_size,
                              hipStream_t stream) {
    const float* coord     = (const float*)d_in[0];
    const float* node_feat = (const float*)d_in[1];
    const int*   edge_index= (const int*)  d_in[2];
    const float* ff_coeff  = (const float*)d_in[3];
    const float* ew1 = (const float*)d_in[4];
    const float* eb1 = (const float*)d_in[5];
    const float* ew2 = (const float*)d_in[6];
    const float* eb2 = (const float*)d_in[7];
    const float* cw1 = (const float*)d_in[8];
    const float* cb1 = (const float*)d_in[9];
    const float* cw2 = (const float*)d_in[10];
    const float* nw1 = (const float*)d_in[11];
    const float* nb1 = (const float*)d_in[12];
    const float* nw2 = (const float*)d_in[13];
    const float* nb2 = (const float*)d_in[14];

    const int N = in_sizes[0] / 3;   // coord [N,3]
    const int E = in_sizes[2] / 2;   // edge_index [2,E]

    // workspace: agg_h [N,32] | agg_c [N,3] | counts [N]
    float* agg_h  = (float*)d_ws;
    float* agg_c  = agg_h + (size_t)N * 32;
    float* counts = agg_c + (size_t)N * 3;
    hipMemsetAsync(d_ws, 0, (size_t)N * 36 * sizeof(float), stream);

    egc_edge_kernel<<<(E + 255) / 256, 256, 0, stream>>>(
        coord, node_feat, edge_index, ff_coeff,
        ew1, eb1, ew2, eb2, cw1, cb1, cw2,
        agg_h, agg_c, counts, E);

    float* out_node  = (float*)d_out;             // [N,32] first (return order)
    float* out_coord = out_node + (size_t)N * 32; // then [N,3]

    egc_node_kernel<<<(N + 255) / 256, 256, 0, stream>>>(
        coord, node_feat, agg_h, agg_c, counts,
        nw1, nb1, nw2, nb2, out_node, out_coord, N);
}

// Round 5
// 767.845 us; speedup vs baseline: 4.1543x; 4.1543x over previous
//
#include <hip/hip_runtime.h>
#include <math.h>

#ifndef M_PIf
#define M_PIf 3.14159265358979323846f
#endif

__device__ __forceinline__ float silu_f(float x) {
    return x / (1.0f + __expf(-x));
}

// ---------------- shared-LDS layout for edge weights (floats) ----------------
#define EW1_OFF 0        // 72*32 = 2304
#define EB1_OFF 2304     // 32
#define EW2_OFF 2336     // 32*32 = 1024
#define EB2_OFF 3360     // 32
#define CW1_OFF 3392     // 32*32 = 1024
#define CB1_OFF 4416     // 32
#define CW2_OFF 4448     // 32
#define EDGE_W_TOTAL 4480

// Stage all edge-path weights into LDS (uniform broadcast reads afterwards).
__device__ __forceinline__ void stage_edge_weights(
    float* sw,
    const float* __restrict__ ew1, const float* __restrict__ eb1,
    const float* __restrict__ ew2, const float* __restrict__ eb2,
    const float* __restrict__ cw1, const float* __restrict__ cb1,
    const float* __restrict__ cw2)
{
    for (int t = threadIdx.x; t < 2304; t += 256) sw[EW1_OFF + t] = ew1[t];
    for (int t = threadIdx.x; t < 32;   t += 256) sw[EB1_OFF + t] = eb1[t];
    for (int t = threadIdx.x; t < 1024; t += 256) sw[EW2_OFF + t] = ew2[t];
    for (int t = threadIdx.x; t < 32;   t += 256) sw[EB2_OFF + t] = eb2[t];
    for (int t = threadIdx.x; t < 1024; t += 256) sw[CW1_OFF + t] = cw1[t];
    for (int t = threadIdx.x; t < 32;   t += 256) sw[CB1_OFF + t] = cb1[t];
    for (int t = threadIdx.x; t < 32;   t += 256) sw[CW2_OFF + t] = cw2[t];
}

// Per-edge MLP core: computes m[32], coord_diff, and coord weight w.
__device__ __forceinline__ void edge_core(
    const float* __restrict__ sw,
    const float* __restrict__ coord,
    const float* __restrict__ node_feat,
    const float* __restrict__ ff_coeff,
    int i, int j,
    float* __restrict__ m,           // out [32]
    float& cdx, float& cdy, float& cdz, float& w)
{
    const float cix = coord[3*(size_t)i+0], ciy = coord[3*(size_t)i+1], ciz = coord[3*(size_t)i+2];
    const float cjx = coord[3*(size_t)j+0], cjy = coord[3*(size_t)j+1], cjz = coord[3*(size_t)j+2];
    cdx = cix - cjx; cdy = ciy - cjy; cdz = ciz - cjz;
    const float radial = cdx*cdx + cdy*cdy + cdz*cdz;

    float ff[8];
    #pragma unroll
    for (int k = 0; k < 4; ++k) {
        float xp = (2.0f * M_PIf) * radial * ff_coeff[k];
        float s, c;
        sincosf(xp, &s, &c);   // xp can be O(500) rad: need accurate range reduction
        ff[k]     = c;
        ff[4 + k] = s;
    }

    // ---- edge MLP layer 1: in[72] @ ew1[72,32] + eb1 ----
    float acc[32];
    #pragma unroll
    for (int o = 0; o < 32; ++o) acc[o] = sw[EB1_OFF + o];

    {
        const float4* nfi4 = reinterpret_cast<const float4*>(node_feat + (size_t)i * 32);
        for (int q = 0; q < 8; ++q) {
            float4 v = nfi4[q];
            float xs[4] = {v.x, v.y, v.z, v.w};
            const float* wr = &sw[EW1_OFF + q * 4 * 32];
            #pragma unroll
            for (int kk = 0; kk < 4; ++kk) {
                #pragma unroll
                for (int o = 0; o < 32; ++o)
                    acc[o] = fmaf(xs[kk], wr[kk*32 + o], acc[o]);
            }
        }
        const float4* nfj4 = reinterpret_cast<const float4*>(node_feat + (size_t)j * 32);
        for (int q = 0; q < 8; ++q) {
            float4 v = nfj4[q];
            float xs[4] = {v.x, v.y, v.z, v.w};
            const float* wr = &sw[EW1_OFF + (32 + q * 4) * 32];
            #pragma unroll
            for (int kk = 0; kk < 4; ++kk) {
                #pragma unroll
                for (int o = 0; o < 32; ++o)
                    acc[o] = fmaf(xs[kk], wr[kk*32 + o], acc[o]);
            }
        }
        #pragma unroll
        for (int k = 0; k < 8; ++k) {
            const float* wr = &sw[EW1_OFF + (64 + k) * 32];
            #pragma unroll
            for (int o = 0; o < 32; ++o)
                acc[o] = fmaf(ff[k], wr[o], acc[o]);
        }
    }

    float m1[32];
    #pragma unroll
    for (int o = 0; o < 32; ++o) m1[o] = silu_f(acc[o]);

    // ---- edge MLP layer 2 ----
    #pragma unroll
    for (int o = 0; o < 32; ++o) m[o] = sw[EB2_OFF + o];
    #pragma unroll
    for (int h = 0; h < 32; ++h) {
        #pragma unroll
        for (int o = 0; o < 32; ++o)
            m[o] = fmaf(m1[h], sw[EW2_OFF + h*32 + o], m[o]);
    }
    #pragma unroll
    for (int o = 0; o < 32; ++o) m[o] = silu_f(m[o]);

    // ---- coord head ----
    float c1[32];
    #pragma unroll
    for (int o = 0; o < 32; ++o) c1[o] = sw[CB1_OFF + o];
    #pragma unroll
    for (int h = 0; h < 32; ++h) {
        #pragma unroll
        for (int o = 0; o < 32; ++o)
            c1[o] = fmaf(m[h], sw[CW1_OFF + h*32 + o], c1[o]);
    }
    w = 0.0f;
    #pragma unroll
    for (int o = 0; o < 32; ++o) w += silu_f(c1[o]) * sw[CW2_OFF + o];
}

// ================= CSR path =================

// K1: per-edge compute; store m + trans; histogram destination counts.
__global__ __launch_bounds__(256) void egc_edge_csr(
    const float* __restrict__ coord,
    const float* __restrict__ node_feat,
    const int*   __restrict__ edge_index,
    const float* __restrict__ ff_coeff,
    const float* __restrict__ ew1, const float* __restrict__ eb1,
    const float* __restrict__ ew2, const float* __restrict__ eb2,
    const float* __restrict__ cw1, const float* __restrict__ cb1,
    const float* __restrict__ cw2,
    float* __restrict__ m_buf,    // [E,32]
    float* __restrict__ trans4,   // [E,4] (xyz + pad)
    int*   __restrict__ counts,   // [N] histogram of idx_i
    int E)
{
    __shared__ float sw[EDGE_W_TOTAL];
    stage_edge_weights(sw, ew1, eb1, ew2, eb2, cw1, cb1, cw2);
    __syncthreads();

    const int e = blockIdx.x * 256 + threadIdx.x;
    if (e >= E) return;

    const int i = edge_index[e];
    const int j = edge_index[E + e];

    float m[32], cdx, cdy, cdz, w;
    edge_core(sw, coord, node_feat, ff_coeff, i, j, m, cdx, cdy, cdz, w);

    float4* mb = reinterpret_cast<float4*>(m_buf + (size_t)e * 32);
    #pragma unroll
    for (int q = 0; q < 8; ++q) {
        float4 v;
        v.x = m[4*q+0]; v.y = m[4*q+1]; v.z = m[4*q+2]; v.w = m[4*q+3];
        mb[q] = v;
    }
    float4 t; t.x = cdx * w; t.y = cdy * w; t.z = cdz * w; t.w = 0.0f;
    *reinterpret_cast<float4*>(trans4 + (size_t)e * 4) = t;

    atomicAdd(&counts[i], 1);   // fire-and-forget int atomic
}

// K2: single-workgroup exclusive scan of counts[N] -> row_start[N+1].
__global__ __launch_bounds__(1024) void egc_scan(
    const int* __restrict__ counts, int* __restrict__ row_start, int N)
{
    __shared__ int wsum[16];
    __shared__ int carry_s;
    const int tid = threadIdx.x;
    const int lane = tid & 63, wid = tid >> 6;
    if (tid == 0) carry_s = 0;
    __syncthreads();
    for (int base = 0; base < N; base += 1024) {
        const int idx = base + tid;
        const int x = (idx < N) ? counts[idx] : 0;
        // inclusive wave scan
        int incl = x;
        #pragma unroll
        for (int off = 1; off < 64; off <<= 1) {
            int v = __shfl_up(incl, off, 64);
            if (lane >= off) incl += v;
        }
        if (lane == 63) wsum[wid] = incl;
        __syncthreads();
        if (wid == 0) {
            int v = (lane < 16) ? wsum[lane] : 0;
            int s = v;
            #pragma unroll
            for (int off = 1; off < 16; off <<= 1) {
                int t = __shfl_up(s, off, 64);
                if (lane >= off) s += t;
            }
            if (lane < 16) wsum[lane] = s - v;   // exclusive wave offsets
        }
        __syncthreads();
        const int carry = carry_s;
        if (idx < N) row_start[idx] = carry + wsum[wid] + incl - x;
        __syncthreads();
        if (tid == 1023) carry_s = carry + wsum[15] + incl;  // + chunk total
        __syncthreads();
    }
    if (tid == 0) row_start[N] = carry_s;
}

// K3: scatter edge ids into CSR order.
__global__ __launch_bounds__(256) void egc_scatter(
    const int* __restrict__ edge_index,
    const int* __restrict__ row_start,
    int* __restrict__ cursor,
    int* __restrict__ edge_order,
    int E)
{
    const int e = blockIdx.x * 256 + threadIdx.x;
    if (e >= E) return;
    const int i = edge_index[e];
    const int pos = atomicAdd(&cursor[i], 1);
    edge_order[row_start[i] + pos] = e;
}

// K4: per-node gather + node MLP + coord finalize.
#define NW1_OFF 0       // 64*32 = 2048
#define NB1_OFF 2048    // 32
#define NW2_OFF 2080    // 32*32 = 1024
#define NB2_OFF 3104    // 32
#define NODE_W_TOTAL 3136

__global__ __launch_bounds__(256) void egc_node_csr(
    const float* __restrict__ coord,
    const float* __restrict__ node_feat,
    const float* __restrict__ m_buf,
    const float* __restrict__ trans4,
    const int*   __restrict__ row_start,
    const int*   __restrict__ edge_order,
    const float* __restrict__ nw1, const float* __restrict__ nb1,
    const float* __restrict__ nw2, const float* __restrict__ nb2,
    float* __restrict__ out_node,   // [N,32]
    float* __restrict__ out_coord,  // [N,3]
    int N)
{
    __shared__ float sw[NODE_W_TOTAL];
    for (int t = threadIdx.x; t < 2048; t += 256) sw[NW1_OFF + t] = nw1[t];
    for (int t = threadIdx.x; t < 32;   t += 256) sw[NB1_OFF + t] = nb1[t];
    for (int t = threadIdx.x; t < 1024; t += 256) sw[NW2_OFF + t] = nw2[t];
    for (int t = threadIdx.x; t < 32;   t += 256) sw[NB2_OFF + t] = nb2[t];
    __syncthreads();

    const int n = blockIdx.x * 256 + threadIdx.x;
    if (n >= N) return;

    const int rs = row_start[n];
    const int re = row_start[n + 1];

    float agg[32];
    #pragma unroll
    for (int o = 0; o < 32; ++o) agg[o] = 0.0f;
    float acx = 0.0f, acy = 0.0f, acz = 0.0f;

    for (int k = rs; k < re; ++k) {
        const int e = edge_order[k];
        const float4* mb = reinterpret_cast<const float4*>(m_buf + (size_t)e * 32);
        #pragma unroll
        for (int q = 0; q < 8; ++q) {
            float4 v = mb[q];
            agg[4*q+0] += v.x; agg[4*q+1] += v.y; agg[4*q+2] += v.z; agg[4*q+3] += v.w;
        }
        float4 t = *reinterpret_cast<const float4*>(trans4 + (size_t)e * 4);
        acx += t.x; acy += t.y; acz += t.z;
    }

    float nf[32];
    {
        const float4* nf4 = reinterpret_cast<const float4*>(node_feat + (size_t)n * 32);
        #pragma unroll
        for (int q = 0; q < 8; ++q) {
            float4 v = nf4[q];
            nf[4*q+0] = v.x; nf[4*q+1] = v.y; nf[4*q+2] = v.z; nf[4*q+3] = v.w;
        }
    }

    // h1 = silu([nf, agg] @ nw1 + nb1)
    float acc[32];
    #pragma unroll
    for (int o = 0; o < 32; ++o) acc[o] = sw[NB1_OFF + o];
    #pragma unroll
    for (int k = 0; k < 32; ++k) {
        #pragma unroll
        for (int o = 0; o < 32; ++o)
            acc[o] = fmaf(nf[k], sw[NW1_OFF + k*32 + o], acc[o]);
    }
    #pragma unroll
    for (int k = 0; k < 32; ++k) {
        #pragma unroll
        for (int o = 0; o < 32; ++o)
            acc[o] = fmaf(agg[k], sw[NW1_OFF + (32+k)*32 + o], acc[o]);
    }
    float h1[32];
    #pragma unroll
    for (int o = 0; o < 32; ++o) h1[o] = silu_f(acc[o]);

    float h2[32];
    #pragma unroll
    for (int o = 0; o < 32; ++o) h2[o] = sw[NB2_OFF + o];
    #pragma unroll
    for (int k = 0; k < 32; ++k) {
        #pragma unroll
        for (int o = 0; o < 32; ++o)
            h2[o] = fmaf(h1[k], sw[NW2_OFF + k*32 + o], h2[o]);
    }

    {
        float4* on4 = reinterpret_cast<float4*>(out_node + (size_t)n * 32);
        #pragma unroll
        for (int q = 0; q < 8; ++q) {
            float4 v;
            v.x = nf[4*q+0] + h2[4*q+0];
            v.y = nf[4*q+1] + h2[4*q+1];
            v.z = nf[4*q+2] + h2[4*q+2];
            v.w = nf[4*q+3] + h2[4*q+3];
            on4[q] = v;
        }
    }

    const float deg = (float)(re - rs);
    const float inv = 1.0f / fmaxf(deg, 1.0f);
    out_coord[(size_t)n*3 + 0] = coord[(size_t)n*3 + 0] + acx * inv;
    out_coord[(size_t)n*3 + 1] = coord[(size_t)n*3 + 1] + acy * inv;
    out_coord[(size_t)n*3 + 2] = coord[(size_t)n*3 + 2] + acz * inv;
}

// ================= fallback (atomic) path — known-good =================

__global__ __launch_bounds__(256) void egc_edge_fb(
    const float* __restrict__ coord,
    const float* __restrict__ node_feat,
    const int*   __restrict__ edge_index,
    const float* __restrict__ ff_coeff,
    const float* __restrict__ ew1, const float* __restrict__ eb1,
    const float* __restrict__ ew2, const float* __restrict__ eb2,
    const float* __restrict__ cw1, const float* __restrict__ cb1,
    const float* __restrict__ cw2,
    float* __restrict__ agg_h, float* __restrict__ agg_c, float* __restrict__ counts,
    int E)
{
    __shared__ float sw[EDGE_W_TOTAL];
    stage_edge_weights(sw, ew1, eb1, ew2, eb2, cw1, cb1, cw2);
    __syncthreads();

    const int e = blockIdx.x * 256 + threadIdx.x;
    if (e >= E) return;
    const int i = edge_index[e];
    const int j = edge_index[E + e];

    float m[32], cdx, cdy, cdz, w;
    edge_core(sw, coord, node_feat, ff_coeff, i, j, m, cdx, cdy, cdz, w);

    float* dst = agg_h + (size_t)i * 32;
    #pragma unroll
    for (int o = 0; o < 32; ++o) atomicAdd(&dst[o], m[o]);
    atomicAdd(&agg_c[(size_t)i*3 + 0], cdx * w);
    atomicAdd(&agg_c[(size_t)i*3 + 1], cdy * w);
    atomicAdd(&agg_c[(size_t)i*3 + 2], cdz * w);
    atomicAdd(&counts[i], 1.0f);
}

__global__ __launch_bounds__(256) void egc_node_fb(
    const float* __restrict__ coord,
    const float* __restrict__ node_feat,
    const float* __restrict__ agg_h,
    const float* __restrict__ agg_c,
    const float* __restrict__ counts,
    const float* __restrict__ nw1, const float* __restrict__ nb1,
    const float* __restrict__ nw2, const float* __restrict__ nb2,
    float* __restrict__ out_node, float* __restrict__ out_coord, int N)
{
    __shared__ float sw[NODE_W_TOTAL];
    for (int t = threadIdx.x; t < 2048; t += 256) sw[NW1_OFF + t] = nw1[t];
    for (int t = threadIdx.x; t < 32;   t += 256) sw[NB1_OFF + t] = nb1[t];
    for (int t = threadIdx.x; t < 1024; t += 256) sw[NW2_OFF + t] = nw2[t];
    for (int t = threadIdx.x; t < 32;   t += 256) sw[NB2_OFF + t] = nb2[t];
    __syncthreads();

    const int n = blockIdx.x * 256 + threadIdx.x;
    if (n >= N) return;

    float nf[32];
    {
        const float4* nf4 = reinterpret_cast<const float4*>(node_feat + (size_t)n * 32);
        #pragma unroll
        for (int q = 0; q < 8; ++q) {
            float4 v = nf4[q];
            nf[4*q+0] = v.x; nf[4*q+1] = v.y; nf[4*q+2] = v.z; nf[4*q+3] = v.w;
        }
    }
    float acc[32];
    #pragma unroll
    for (int o = 0; o < 32; ++o) acc[o] = sw[NB1_OFF + o];
    #pragma unroll
    for (int k = 0; k < 32; ++k) {
        #pragma unroll
        for (int o = 0; o < 32; ++o)
            acc[o] = fmaf(nf[k], sw[NW1_OFF + k*32 + o], acc[o]);
    }
    {
        const float4* ah4 = reinterpret_cast<const float4*>(agg_h + (size_t)n * 32);
        #pragma unroll
        for (int q = 0; q < 8; ++q) {
            float4 v = ah4[q];
            float xs[4] = {v.x, v.y, v.z, v.w};
            const float* wr = &sw[NW1_OFF + (32 + q * 4) * 32];
            #pragma unroll
            for (int kk = 0; kk < 4; ++kk) {
                #pragma unroll
                for (int o = 0; o < 32; ++o)
                    acc[o] = fmaf(xs[kk], wr[kk*32 + o], acc[o]);
            }
        }
    }
    float h1[32];
    #pragma unroll
    for (int o = 0; o < 32; ++o) h1[o] = silu_f(acc[o]);
    float h2[32];
    #pragma unroll
    for (int o = 0; o < 32; ++o) h2[o] = sw[NB2_OFF + o];
    #pragma unroll
    for (int k = 0; k < 32; ++k) {
        #pragma unroll
        for (int o = 0; o < 32; ++o)
            h2[o] = fmaf(h1[k], sw[NW2_OFF + k*32 + o], h2[o]);
    }
    {
        float4* on4 = reinterpret_cast<float4*>(out_node + (size_t)n * 32);
        #pragma unroll
        for (int q = 0; q < 8; ++q) {
            float4 v;
            v.x = nf[4*q+0] + h2[4*q+0];
            v.y = nf[4*q+1] + h2[4*q+1];
            v.z = nf[4*q+2] + h2[4*q+2];
            v.w = nf[4*q+3] + h2[4*q+3];
            on4[q] = v;
        }
    }
    const float cnt = fmaxf(counts[n], 1.0f);
    const float inv = 1.0f / cnt;
    out_coord[(size_t)n*3 + 0] = coord[(size_t)n*3 + 0] + agg_c[(size_t)n*3 + 0] * inv;
    out_coord[(size_t)n*3 + 1] = coord[(size_t)n*3 + 1] + agg_c[(size_t)n*3 + 1] * inv;
    out_coord[(size_t)n*3 + 2] = coord[(size_t)n*3 + 2] + agg_c[(size_t)n*3 + 2] * inv;
}

// ================= launch =================

extern "C" void kernel_launch(void* const* d_in, const int* in_sizes, int n_in,
                              void* d_out, int out_size, void* d_ws, size_t ws_size,
                              hipStream_t stream) {
    const float* coord     = (const float*)d_in[0];
    const float* node_feat = (const float*)d_in[1];
    const int*   edge_index= (const int*)  d_in[2];
    const float* ff_coeff  = (const float*)d_in[3];
    const float* ew1 = (const float*)d_in[4];
    const float* eb1 = (const float*)d_in[5];
    const float* ew2 = (const float*)d_in[6];
    const float* eb2 = (const float*)d_in[7];
    const float* cw1 = (const float*)d_in[8];
    const float* cb1 = (const float*)d_in[9];
    const float* cw2 = (const float*)d_in[10];
    const float* nw1 = (const float*)d_in[11];
    const float* nb1 = (const float*)d_in[12];
    const float* nw2 = (const float*)d_in[13];
    const float* nb2 = (const float*)d_in[14];

    const int N = in_sizes[0] / 3;   // coord [N,3]
    const int E = in_sizes[2] / 2;   // edge_index [2,E]

    float* out_node  = (float*)d_out;             // [N,32]
    float* out_coord = out_node + (size_t)N * 32; // [N,3]

    // CSR workspace layout (element offsets; all regions 16B-aligned)
    const size_t m_off      = 0;                              // E*32 floats
    const size_t t_off      = m_off + (size_t)E * 32;         // E*4 floats
    const size_t eo_off     = t_off + (size_t)E * 4;          // E ints
    const size_t cnt_off    = eo_off + (size_t)E;             // N ints
    const size_t cur_off    = cnt_off + (size_t)N;            // N ints
    const size_t rs_off     = cur_off + (size_t)N;            // N+1 ints
    const size_t need_bytes = (rs_off + (size_t)N + 1) * 4 + 256;

    if (ws_size >= need_bytes) {
        float* m_buf      = (float*)d_ws + m_off;
        float* trans4     = (float*)d_ws + t_off;
        int*   edge_order = (int*)d_ws + eo_off;
        int*   counts     = (int*)d_ws + cnt_off;
        int*   cursor     = (int*)d_ws + cur_off;
        int*   row_start  = (int*)d_ws + rs_off;

        // zero counts + cursor (adjacent)
        hipMemsetAsync(counts, 0, (size_t)2 * N * sizeof(int), stream);

        egc_edge_csr<<<(E + 255) / 256, 256, 0, stream>>>(
            coord, node_feat, edge_index, ff_coeff,
            ew1, eb1, ew2, eb2, cw1, cb1, cw2,
            m_buf, trans4, counts, E);

        egc_scan<<<1, 1024, 0, stream>>>(counts, row_start, N);

        egc_scatter<<<(E + 255) / 256, 256, 0, stream>>>(
            edge_index, row_start, cursor, edge_order, E);

        egc_node_csr<<<(N + 255) / 256, 256, 0, stream>>>(
            coord, node_feat, m_buf, trans4, row_start, edge_order,
            nw1, nb1, nw2, nb2, out_node, out_coord, N);
    } else {
        // fallback: atomic scatter path
        float* agg_h  = (float*)d_ws;
        float* agg_c  = agg_h + (size_t)N * 32;
        float* counts = agg_c + (size_t)N * 3;
        hipMemsetAsync(d_ws, 0, (size_t)N * 36 * sizeof(float), stream);

        egc_edge_fb<<<(E + 255) / 256, 256, 0, stream>>>(
            coord, node_feat, edge_index, ff_coeff,
            ew1, eb1, ew2, eb2, cw1, cb1, cw2,
            agg_h, agg_c, counts, E);

        egc_node_fb<<<(N + 255) / 256, 256, 0, stream>>>(
            coord, node_feat, agg_h, agg_c, counts,
            nw1, nb1, nw2, nb2, out_node, out_coord, N);
    }
}